// Round 10
// baseline (772.968 us; speedup 1.0000x reference)
//
#include <hip/hip_runtime.h>

// DenseNet ValueModel, bf16 3-term split MFMA, v8: anti-stall inner loop.
// Accounting on v7 (488us): MFMA pipe 47K cyc/gen (24%), reduce ~50K, and
// ~120K cyc/gen of per-wave memory stalls (2-deep B, A-reads at use, 3
// serial MFMAs per chunk). v8: 3 acc chains BY TERM (P=al*bh, Q=ah*bl,
// R=ah*bh -> intra-chunk MFMAs independent), B 4-deep + A 2-deep named
// prefetch slots, zero-VALU B addressing (CHUNK_STRIDE 4096, n1 padded to
// 32 lanes in pre-kernel, SGPR base + l*16 + imm offsets). Reduce/epilogue
// byte-identical to PASSING v6. All guards wave-uniform; every executed
// MFMA has ci<chunks so A-garbage stays confined to dead C rows (v6 rule).

#define IN 16
#define KJ 50
#define NL 25
#define FW 1266
#define TR 24
#define NB 1366          // ceil(32768/24); last block: 8 live rows
#define BTOT 32768
#define XSTR 1272        // u16/row (>= 1266, mult of 8)
#define NTHREADS 1024
#define XLO_OFF 61056    // 24*1272*2
#define SLAB_OFF 122112  // 2*61056
#define BIAS_OFF 154880  // + 8*16*64*4 slab (32768 B)
#define LDS_BYTES 159880 // <= 163840 -> 1 block/CU, 4 waves/SIMD
#define TOTAL_CHUNKS 973 // sum_{i<25} ceil((16+50i)/16); d_ws = 973*4096 = 3,985,408 B

typedef __attribute__((ext_vector_type(8))) short bf16x8;
typedef __attribute__((ext_vector_type(16))) float f32x16;

__device__ __forceinline__ unsigned short bf16_hi(float x, float* hif) {
    unsigned u = __float_as_uint(x);
    unsigned h = (u + 0x8000u) >> 16;
    *hif = __uint_as_float(h << 16);
    return (unsigned short)h;
}
__device__ __forceinline__ unsigned short bf16_rnd(float x) {
    return (unsigned short)((__float_as_uint(x) + 0x8000u) >> 16);
}

// ---------------- pre-kernel: split + fragment W into d_ws ----------------
// Chunk layout (4096 B): [n0 hi 1KB][n0 lo 1KB][n1 hi 1KB][n1 lo 1KB],
// lane l*16; n0: j = l&31; n1: j = 32+(l&31) if (l&31)<18 else ZERO (pad).
__device__ __forceinline__ void split8(const float* __restrict__ rowp, int kb, int width,
                                       unsigned hi[4], unsigned lo[4]) {
#pragma unroll
    for (int p = 0; p < 4; ++p) {
        unsigned h2[2], l2[2];
#pragma unroll
        for (int q = 0; q < 2; ++q) {
            int k = kb + p * 2 + q;
            float v = (k < width) ? rowp[k] : 0.f;
            float hif;
            unsigned short h = bf16_hi(v, &hif);
            h2[q] = h;
            l2[q] = bf16_rnd(v - hif);
        }
        hi[p] = h2[0] | (h2[1] << 16);
        lo[p] = l2[0] | (l2[1] << 16);
    }
}

__global__ __launch_bounds__(64, 1) void split_w(const float* __restrict__ Ws,
                                                 char* __restrict__ wsbuf) {
    int rem = blockIdx.x, layer = 0;
    size_t off = 0;
    for (;;) {
        int c = (IN + KJ * layer + 15) >> 4;
        if (rem < c) break;
        rem -= c; off += (size_t)c << 12; ++layer;
    }
    const int ci = rem, k0 = ci << 4, width = IN + KJ * layer;
    const float* Wl = Ws + (size_t)layer * KJ * FW;
    char* base = wsbuf + off + ((size_t)ci << 12);
    const int l = threadIdx.x, ll = l & 31, kh = l >> 5;
    const int kb = k0 + kh * 8;

    unsigned hi[4], lo[4];
    split8(Wl + (size_t)ll * FW, kb, width, hi, lo);          // n0: j = ll (< 50)
    *reinterpret_cast<uint4*>(base + l * 16)        = make_uint4(hi[0], hi[1], hi[2], hi[3]);
    *reinterpret_cast<uint4*>(base + 1024 + l * 16) = make_uint4(lo[0], lo[1], lo[2], lo[3]);
    uint4 zh = make_uint4(0u, 0u, 0u, 0u), zl = zh;
    if (ll < 18) {                                            // n1: j = 32+ll (<= 49)
        split8(Wl + (size_t)(32 + ll) * FW, kb, width, hi, lo);
        zh = make_uint4(hi[0], hi[1], hi[2], hi[3]);
        zl = make_uint4(lo[0], lo[1], lo[2], lo[3]);
    }
    *reinterpret_cast<uint4*>(base + 2048 + l * 16) = zh;     // dead lanes: zeros
    *reinterpret_cast<uint4*>(base + 3072 + l * 16) = zl;
}

// B slot load: SGPR-uniform chunk base + per-lane l16; zeros past chunks.
#define LB(S, CI) { bf16x8 z_ = {0,0,0,0,0,0,0,0}; S##h = z_; S##l = z_;           \
    if ((CI) < chunks) { const char* cb_ = wb + ((size_t)(CI) << 12);              \
        S##h = *(const bf16x8*)(cb_ + l16);                                        \
        S##l = *(const bf16x8*)(cb_ + 1024 + l16); } }

// A slot load (LDS, 2 x b128); guarded so reads stay in the proven envelope.
#define LA(S, CI) if ((CI) < chunks) { const int kof_ = (CI) << 4;                 \
    S##h = *(const bf16x8*)(xrh + kof_);                                           \
    S##l = *(const bf16x8*)(xrl + kof_); }

// 3 term-split MFMAs -> 3 INDEPENDENT chains (P: al*bh, Q: ah*bl, R: ah*bh)
#define MF3(S, T) {                                                                \
    aP = __builtin_amdgcn_mfma_f32_32x32x16_bf16(S##l, T##h, aP, 0, 0, 0);         \
    aQ = __builtin_amdgcn_mfma_f32_32x32x16_bf16(S##h, T##l, aQ, 0, 0, 0);         \
    aR = __builtin_amdgcn_mfma_f32_32x32x16_bf16(S##h, T##h, aR, 0, 0, 0); }

// ---------------- main kernel: 1024 threads, 16 waves ----------------
__global__ __launch_bounds__(NTHREADS, 4) void densenet_mfma(
    const float* __restrict__ state, const char* __restrict__ wsbuf,
    const float* __restrict__ bs,    const float* __restrict__ Wout,
    const float* __restrict__ bout,  float* __restrict__ out)
{
    __shared__ __align__(16) char lds[LDS_BYTES];
    unsigned short* xhi = (unsigned short*)lds;
    unsigned short* xlo = (unsigned short*)(lds + XLO_OFF);
    float* slab  = (float*)(lds + SLAB_OFF);   // h1: [q8][row16][col64]; h2: [q8][row8][col64]
    float* biasl = (float*)(lds + BIAS_OFF);

    const int tid = threadIdx.x;
    const int w   = tid >> 6;       // wave 0..15
    const int l   = tid & 63;
    const int ll  = l & 31, kh = l >> 5;
    const int l16 = l << 4;
    const int kq  = w & 7;          // K-chunk residue this wave owns
    const int n   = w >> 3;         // N-tile this wave owns
    const long row0 = (long)blockIdx.x * TR;

    // zero x planes (masks k-tails, dead batch rows; cols >= width stay zero
    // until their producing layer writes them)
    {
        unsigned* p = (unsigned*)lds;
        for (int i = tid; i < SLAB_OFF / 4; i += NTHREADS) p[i] = 0u;
    }
    for (int i = tid; i < NL * KJ; i += NTHREADS) biasl[i] = bs[i];
    __syncthreads();
    if (tid < TR * IN) {
        int r = tid >> 4, c = tid & 15;
        if (row0 + r < BTOT) {
            float v = state[(row0 + r) * IN + c];
            float hif;
            xhi[r * XSTR + c] = bf16_hi(v, &hif);
            xlo[r * XSTR + c] = bf16_rnd(v - hif);
        }
    }
    __syncthreads();   // x init visible to all waves

    const unsigned short* xrh = xhi + ll * XSTR + (kh << 3);   // A-row base (rows 24..31:
    const unsigned short* xrl = xlo + ll * XSTR + (kh << 3);   // in-LDS garbage, dead C rows)

    int width = IN;
    size_t wofs = 0;
    for (int layer = 0; layer < NL; ++layer) {
        const int chunks = (width + 15) >> 4;
        const char* wb = wsbuf + wofs + (n ? 2048 : 0);

        f32x16 aP, aQ, aR;
#pragma unroll
        for (int i = 0; i < 16; ++i) { aP[i] = 0.f; aQ[i] = 0.f; aR[i] = 0.f; }

        // pipeline: B 4-deep (B0..B3), A 2-deep (A0,A1); all slots named.
        bf16x8 zz = {0,0,0,0,0,0,0,0};
        bf16x8 A0h = zz, A0l = zz, A1h = zz, A1l = zz;
        bf16x8 B0h, B0l, B1h, B1l, B2h, B2l, B3h, B3l;
        LB(B0, kq) LB(B1, kq + 8) LB(B2, kq + 16) LB(B3, kq + 24)
        LA(A0, kq) LA(A1, kq + 8)
        for (int c0 = kq; c0 < chunks; c0 += 32) {
            MF3(A0, B0)
            LA(A0, c0 + 16) LB(B0, c0 + 32)
            if (c0 + 8 < chunks) { MF3(A1, B1) }
            LA(A1, c0 + 24) LB(B1, c0 + 40)
            if (c0 + 16 < chunks) { MF3(A0, B2) }
            LA(A0, c0 + 32) LB(B2, c0 + 48)
            if (c0 + 24 < chunks) { MF3(A1, B3) }
            LA(A1, c0 + 40) LB(B3, c0 + 56)
        }

        // ---- phase h1: acc regs 0..7 <-> C rows 0..15 ----
        // C layout (verified): col = l&31, row = (r&3) + 8*(r>>2) + 4*kh
        {
            float* s1 = slab + kq * 1024 + n * 32 + ll;
#pragma unroll
            for (int r = 0; r < 8; ++r) {
                int crow = (r & 3) + 8 * (r >> 2) + 4 * kh;
                s1[crow * 64] = (aP[r] + aQ[r]) + aR[r];
            }
        }
        __syncthreads();   // (1) h1 slab complete; all A-reads done
        {
            int row = tid >> 6, j = tid & 63;   // 16 x 64 == 1024: one elem/thread
            float s = 0.f;
#pragma unroll
            for (int q = 0; q < 8; ++q) s += slab[q * 1024 + row * 64 + j];
            if (j < KJ) {
                s += biasl[layer * KJ + j];
                s = (s > 0.f) ? s : 0.01f * s;
                float hif;
                xhi[row * XSTR + width + j] = bf16_hi(s, &hif);
                xlo[row * XSTR + width + j] = bf16_rnd(s - hif);
            }
        }
        __syncthreads();   // (2) h1 slab reads done -> region reusable
        // ---- phase h2: acc regs 8..11 <-> C rows 16..23 ----
        {
            float* s2 = slab + kq * 512 + n * 32 + ll;
#pragma unroll
            for (int r = 0; r < 4; ++r) {
                int lrow = (r & 3) + 4 * kh;    // 0..7 -> global rows 16..23
                s2[lrow * 64] = (aP[8 + r] + aQ[8 + r]) + aR[8 + r];
            }
        }
        __syncthreads();   // (3)
        if (tid < 512) {
            int lrow = tid >> 6, j = tid & 63;
            int row = 16 + lrow;
            float s = 0.f;
#pragma unroll
            for (int q = 0; q < 8; ++q) s += slab[q * 512 + lrow * 64 + j];
            if (j < KJ) {
                s += biasl[layer * KJ + j];
                s = (s > 0.f) ? s : 0.01f * s;
                float hif;
                xhi[row * XSTR + width + j] = bf16_hi(s, &hif);
                xlo[row * XSTR + width + j] = bf16_rnd(s - hif);
            }
        }
        __syncthreads();   // (4) new x cols visible; slab free

        width += KJ;
        wofs += (size_t)chunks << 12;
    }

    // epilogue: out[r] = x[r] . Wout + bout ; rows 0..15 -> waves 0..15,
    // rows 16..23 -> waves 0..7 (second pass). Wout straight from global (L2-hot).
    const float b0 = bout[0];
#pragma unroll
    for (int rr = 0; rr < 2; ++rr) {
        if (rr == 1 && w >= 8) break;
        const int row = rr ? 16 + w : w;
        const long grow = row0 + row;
        const unsigned short* xh = xhi + row * XSTR;
        const unsigned short* xl = xlo + row * XSTR;
        float s = 0.f;
#pragma unroll
        for (int it = 0; it < 19; ++it) {   // 19*64 = 1216
            int k = l + (it << 6);
            float xv = __uint_as_float((unsigned)xh[k] << 16)
                     + __uint_as_float((unsigned)xl[k] << 16);
            s += xv * Wout[k];
        }
        {
            int k = 1216 + l;
            if (k < FW) {
                float xv = __uint_as_float((unsigned)xh[k] << 16)
                         + __uint_as_float((unsigned)xl[k] << 16);
                s += xv * Wout[k];
            }
        }
#pragma unroll
        for (int m = 32; m >= 1; m >>= 1) s += __shfl_xor(s, m, 64);
        if (l == 0 && grow < BTOT) out[grow] = s + b0;
    }
}

extern "C" void kernel_launch(void* const* d_in, const int* in_sizes, int n_in,
                              void* d_out, int out_size, void* d_ws, size_t ws_size,
                              hipStream_t stream) {
    const float* state = (const float*)d_in[0];
    const float* Ws    = (const float*)d_in[1];
    const float* bs    = (const float*)d_in[2];
    const float* Wout  = (const float*)d_in[3];
    const float* bout  = (const float*)d_in[4];
    float* out = (float*)d_out;
    char* wsbuf = (char*)d_ws;   // needs TOTAL_CHUNKS*4096 = 3,985,408 B

    split_w<<<dim3(TOTAL_CHUNKS), dim3(64), 0, stream>>>(Ws, wsbuf);
    densenet_mfma<<<dim3(NB), dim3(NTHREADS), 0, stream>>>(state, wsbuf, bs, Wout, bout, out);
}